// Round 13
// baseline (194.910 us; speedup 1.0000x reference)
//
#include <hip/hip_runtime.h>
#include <math.h>

#define B_ 2
#define T_ 1024
#define D_ 1024
#define H_ 16
#define NA_ 3328   // qkvp width: 3*D + 4*64 lines

typedef __attribute__((ext_vector_type(8))) short bf16x8;
typedef __attribute__((ext_vector_type(4))) float f32x4;

__device__ inline unsigned short f2bf(float x) {
  return (unsigned short)((__float_as_uint(x) + 0x8000u) >> 16);
}
// pack two f32 -> dword of 2 bf16 (lo in low half)
__device__ inline unsigned bfpack(float lo, float hi) {
  unsigned a = __float_as_uint(hi) + 0x8000u;
  unsigned b = __float_as_uint(lo) + 0x8000u;
  return __builtin_amdgcn_perm(a, b, 0x07060302);
}
__device__ inline void hl_split(float x, unsigned short& h, unsigned short& l) {
  unsigned short hh = f2bf(x);
  float hf = __uint_as_float(((unsigned)hh) << 16);
  l = f2bf(x - hf);
  h = hh;
}

// ===== bf16 MFMA GEMM core: 64x128 tile, 256 threads (2x2 waves), BK=32, dbuf =====
// f32 global reads, f32->bf16 conversion during staging (R5/R12-measured clean/fast),
// slot-major LDS: As[2][4 slot][64 row][16B], Bs[2][4 slot][128 row][16B].
#define H_PRO()                                                                \
  const int tid = threadIdx.x;                                                 \
  const int w = tid >> 6, lane = tid & 63;                                     \
  const int lr = lane & 15, g = lane >> 4;                                     \
  const int wm = (w >> 1) * 32, wn = (w & 1) * 64;                             \
  const int arow = tid & 63, aslot = tid >> 6;                                 \
  const int brow = tid & 127, bs2 = (tid >> 7) * 2;

#define H_LOADA(d, s) {                                                        \
  d[0] = *(const float4*)(Ap + (s) * 32);                                      \
  d[1] = *(const float4*)(Ap + (s) * 32 + 4); }
#define H_LOADB(d, s) {                                                        \
  d[0] = *(const float4*)(Bp + (s) * 32);                                      \
  d[1] = *(const float4*)(Bp + (s) * 32 + 4);                                  \
  d[2] = *(const float4*)(Bp + (s) * 32 + 8);                                  \
  d[3] = *(const float4*)(Bp + (s) * 32 + 12); }
#define H_STORE(bi, a, b) {                                                    \
  unsigned char* SA_ = As + (bi) * 4096;                                       \
  *(uint4*)(SA_ + aslot * 1024 + arow * 16) =                                  \
      make_uint4(bfpack(a[0].x, a[0].y), bfpack(a[0].z, a[0].w),               \
                 bfpack(a[1].x, a[1].y), bfpack(a[1].z, a[1].w));              \
  unsigned char* SB_ = Bs + (bi) * 8192;                                       \
  *(uint4*)(SB_ + bs2 * 2048 + brow * 16) =                                    \
      make_uint4(bfpack(b[0].x, b[0].y), bfpack(b[0].z, b[0].w),               \
                 bfpack(b[1].x, b[1].y), bfpack(b[1].z, b[1].w));              \
  *(uint4*)(SB_ + (bs2 + 1) * 2048 + brow * 16) =                              \
      make_uint4(bfpack(b[2].x, b[2].y), bfpack(b[2].z, b[2].w),               \
                 bfpack(b[3].x, b[3].y), bfpack(b[3].z, b[3].w)); }
#define H_COMPUTE(bi) {                                                        \
  const unsigned char* SA_ = As + (bi) * 4096;                                 \
  const unsigned char* SB_ = Bs + (bi) * 8192;                                 \
  bf16x8 af[2], bfr[4];                                                        \
  _Pragma("unroll") for (int i = 0; i < 2; ++i)                                \
    af[i] = *(const bf16x8*)(SA_ + g * 1024 + (wm + i * 16 + lr) * 16);        \
  _Pragma("unroll") for (int j = 0; j < 4; ++j)                                \
    bfr[j] = *(const bf16x8*)(SB_ + g * 2048 + (wn + j * 16 + lr) * 16);       \
  _Pragma("unroll") for (int i = 0; i < 2; ++i)                                \
  _Pragma("unroll") for (int j = 0; j < 4; ++j)                                \
    acc[i][j] = __builtin_amdgcn_mfma_f32_16x16x32_bf16(af[i], bfr[j],         \
                                                        acc[i][j], 0, 0, 0); }
#define H_MAIN()                                                               \
  f32x4 acc[2][4];                                                             \
  const f32x4 zf = {0.f, 0.f, 0.f, 0.f};                                       \
  _Pragma("unroll") for (int i = 0; i < 2; ++i)                                \
  _Pragma("unroll") for (int j = 0; j < 4; ++j) acc[i][j] = zf;                \
  float4 a0[2], b0[4], a1[2], b1[4];                                           \
  H_LOADA(a0, 0); H_LOADB(b0, 0);                                              \
  H_STORE(0, a0, b0);                                                          \
  H_LOADA(a1, 1); H_LOADB(b1, 1);                                              \
  __syncthreads();                                                             \
  _Pragma("unroll 1") for (int s = 0; s < 32; s += 2) {                        \
    H_COMPUTE(0);                                                              \
    H_STORE(1, a1, b1);                                                        \
    if (s + 2 < 32) { H_LOADA(a0, s + 2); H_LOADB(b0, s + 2); }                \
    __syncthreads();                                                           \
    H_COMPUTE(1);                                                              \
    if (s + 2 < 32) H_STORE(0, a0, b0);                                        \
    if (s + 3 < 32) { H_LOADA(a1, s + 3); H_LOADB(b1, s + 3); }                \
    __syncthreads();                                                           \
  }

// qkv GEMM: qkvp[2048,3328] f32 = x @ [Wqkv;W1w;W2w;W1r;W2r]^T (+bias cols<3072).
__global__ __launch_bounds__(256) void gemm_qkv(
    const float* __restrict__ A, const float* __restrict__ Wqkv,
    const float* __restrict__ bqkv,
    const float* __restrict__ W1w, const float* __restrict__ W2w,
    const float* __restrict__ W1r, const float* __restrict__ W2r,
    float* __restrict__ C)
{
  __shared__ __align__(16) unsigned char As[2 * 4096];
  __shared__ __align__(16) unsigned char Bs[2 * 8192];
  const int m0 = blockIdx.y * 64, n0 = blockIdx.x * 128;
  H_PRO();
  const float* Ap = A + (size_t)(m0 + arow) * 1024 + aslot * 8;
  const float* Bp;
  {
    const int cg = n0 + brow;
    if (cg < 3072) Bp = Wqkv + (size_t)cg * 1024;
    else {
      const int r2 = cg - 3072;
      const float* Wm = (r2 < 64) ? W1w : (r2 < 128) ? W2w : (r2 < 192) ? W1r : W2r;
      Bp = Wm + (size_t)(r2 & 63) * 1024;
    }
    Bp += bs2 * 8;
  }
  H_MAIN();
#pragma unroll
  for (int i = 0; i < 2; ++i) {
    const int rbase = m0 + wm + i * 16 + 4 * g;
#pragma unroll
    for (int j = 0; j < 4; ++j) {
      const int col = n0 + wn + j * 16 + lr;
      const float bb = (col < 3072) ? bqkv[col] : 0.f;
#pragma unroll
      for (int r = 0; r < 4; ++r)
        C[(size_t)(rbase + r) * NA_ + col] = acc[i][j][r] + bb;
    }
  }
}

// out GEMM: out[2048,1024] f32 = attnout @ Wout^T + bout
__global__ __launch_bounds__(256) void gemm_out(
    const float* __restrict__ A, const float* __restrict__ Bm,
    const float* __restrict__ bias, float* __restrict__ C)
{
  __shared__ __align__(16) unsigned char As[2 * 4096];
  __shared__ __align__(16) unsigned char Bs[2 * 8192];
  const int m0 = blockIdx.y * 64, n0 = blockIdx.x * 128;
  H_PRO();
  const float* Ap = A + (size_t)(m0 + arow) * 1024 + aslot * 8;
  const float* Bp = Bm + (size_t)(n0 + brow) * 1024 + bs2 * 8;
  H_MAIN();
#pragma unroll
  for (int i = 0; i < 2; ++i) {
    const int rbase = m0 + wm + i * 16 + 4 * g;
#pragma unroll
    for (int j = 0; j < 4; ++j) {
      const int col = n0 + wn + j * 16 + lr;
      const float bb = bias[col];
#pragma unroll
      for (int r = 0; r < 4; ++r)
        C[(size_t)(rbase + r) * 1024 + col] = acc[i][j][r] + bb;
    }
  }
}

// ===== fused exterior + causal 6x6 Gram cumsum (Hillis-Steele) -> Jwpk, rdMpk =====
// One block per (b,h); thread handles t in [tid*4, tid*4+4). Lines computed from
// qkvp cols 3072+ inline (phase A: write-lines for Jwpk + Gram; phase B: recompute
// + read-lines for rd_M).
__global__ __launch_bounds__(256) void scan_kernel(
    const float* __restrict__ qkvp,
    unsigned* __restrict__ Jwpk, unsigned* __restrict__ rdMpk)
{
  __shared__ float sc[256][41];   // 41-f32 rows: gcd(41,32)=1 -> spread banks
  const int tid = threadIdx.x;
  const int bh = blockIdx.x;
  const int b = bh >> 4, h = bh & 15;
  const int t0 = tid * 4;

  float L[36];
#pragma unroll
  for (int i = 0; i < 36; ++i) L[i] = 0.f;

  // ---- phase A: write-lines -> Jwpk + local Gram sum L ----
  for (int tt = 0; tt < 4; ++tt) {
    const int t = t0 + tt;
    const size_t rowt = ((size_t)(b * T_) + t) * NA_;
    float4 p1w = make_float4(0.f, 0.f, 0.f, 0.f);
    if (t > 0) p1w = *(const float4*)(qkvp + rowt - NA_ + 3072 + h * 4);
    const float4 p2w = *(const float4*)(qkvp + rowt + 3136 + h * 4);
    const float L0 = p1w.x * p2w.y - p1w.y * p2w.x;
    const float L1 = p1w.x * p2w.z - p1w.z * p2w.x;
    const float L2 = p1w.x * p2w.w - p1w.w * p2w.x;
    const float L3 = p1w.y * p2w.z - p1w.z * p2w.y;
    const float L4 = p1w.y * p2w.w - p1w.w * p2w.y;
    const float L5 = p1w.z * p2w.w - p1w.w * p2w.z;
    const float n = sqrtf(L0 * L0 + L1 * L1 + L2 * L2 + L3 * L3 + L4 * L4 + L5 * L5);
    const float inv = 1.f / fmaxf(n, 1e-12f);
    const float jv[6] = {L5 * inv, -L4 * inv, L3 * inv, L2 * inv, -L1 * inv, L0 * inv};
    unsigned short JH[6], JL[6];
#pragma unroll
    for (int k = 0; k < 6; ++k) hl_split(jv[k], JH[k], JL[k]);
    unsigned* jp = Jwpk + (((size_t)bh * T_ + t) << 4);
    const unsigned h01 = JH[0] | ((unsigned)JH[1] << 16);
    const unsigned h23 = JH[2] | ((unsigned)JH[3] << 16);
    const unsigned h45 = JH[4] | ((unsigned)JH[5] << 16);
    jp[0] = h01; jp[1] = h23; jp[2] = h45;
    jp[3] = JL[0] | ((unsigned)JL[1] << 16);
    jp[4] = JL[2] | ((unsigned)JL[3] << 16);
    jp[5] = JL[4] | ((unsigned)JL[5] << 16);
    jp[6] = h01; jp[7] = h23; jp[8] = h45;
#pragma unroll
    for (int k = 9; k < 16; ++k) jp[k] = 0;
#pragma unroll
    for (int a = 0; a < 6; ++a)
#pragma unroll
      for (int c2 = 0; c2 < 6; ++c2)
        L[a * 6 + c2] = fmaf(jv[a], jv[c2], L[a * 6 + c2]);
  }

  // ---- Hillis-Steele inclusive scan of 36-element Gram blocks ----
  float M[36];
#pragma unroll
  for (int i = 0; i < 36; ++i) M[i] = L[i];
#pragma unroll
  for (int k = 0; k < 9; ++k)
    *(float4*)&sc[tid][k * 4] = make_float4(M[k*4], M[k*4+1], M[k*4+2], M[k*4+3]);
  __syncthreads();
  for (int off = 1; off < 256; off <<= 1) {
    float4 tmp[9];
    const bool act = (tid >= off);
    if (act) {
#pragma unroll
      for (int k = 0; k < 9; ++k) tmp[k] = *(const float4*)&sc[tid - off][k * 4];
    }
    __syncthreads();
    if (act) {
#pragma unroll
      for (int k = 0; k < 9; ++k) {
        M[k*4]   += tmp[k].x; M[k*4+1] += tmp[k].y;
        M[k*4+2] += tmp[k].z; M[k*4+3] += tmp[k].w;
      }
#pragma unroll
      for (int k = 0; k < 9; ++k)
        *(float4*)&sc[tid][k * 4] = make_float4(M[k*4], M[k*4+1], M[k*4+2], M[k*4+3]);
    }
    __syncthreads();
  }

  float Mp[36];
#pragma unroll
  for (int i = 0; i < 36; ++i) Mp[i] = M[i] - L[i];   // exclusive prefix

  // ---- phase B: recompute lines, advance Mp, rd_M -> rdMpk ----
  for (int tt = 0; tt < 4; ++tt) {
    const int t = t0 + tt;
    const size_t rowt = ((size_t)(b * T_) + t) * NA_;
    float4 p1w = make_float4(0.f, 0.f, 0.f, 0.f);
    if (t > 0) p1w = *(const float4*)(qkvp + rowt - NA_ + 3072 + h * 4);
    const float4 p2w = *(const float4*)(qkvp + rowt + 3136 + h * 4);
    const float4 p1r = *(const float4*)(qkvp + rowt + 3200 + h * 4);
    const float4 p2r = *(const float4*)(qkvp + rowt + 3264 + h * 4);
    float jv[6], rv[6];
    {
      const float L0 = p1w.x * p2w.y - p1w.y * p2w.x;
      const float L1 = p1w.x * p2w.z - p1w.z * p2w.x;
      const float L2 = p1w.x * p2w.w - p1w.w * p2w.x;
      const float L3 = p1w.y * p2w.z - p1w.z * p2w.y;
      const float L4 = p1w.y * p2w.w - p1w.w * p2w.y;
      const float L5 = p1w.z * p2w.w - p1w.w * p2w.z;
      const float n = sqrtf(L0*L0 + L1*L1 + L2*L2 + L3*L3 + L4*L4 + L5*L5);
      const float inv = 1.f / fmaxf(n, 1e-12f);
      jv[0] = L5*inv; jv[1] = -L4*inv; jv[2] = L3*inv;
      jv[3] = L2*inv; jv[4] = -L1*inv; jv[5] = L0*inv;
    }
    {
      const float L0 = p1r.x * p2r.y - p1r.y * p2r.x;
      const float L1 = p1r.x * p2r.z - p1r.z * p2r.x;
      const float L2 = p1r.x * p2r.w - p1r.w * p2r.x;
      const float L3 = p1r.y * p2r.z - p1r.z * p2r.y;
      const float L4 = p1r.y * p2r.w - p1r.w * p2r.y;
      const float L5 = p1r.z * p2r.w - p1r.w * p2r.z;
      const float n = sqrtf(L0*L0 + L1*L1 + L2*L2 + L3*L3 + L4*L4 + L5*L5);
      const float inv = 1.f / fmaxf(n, 1e-12f);
      rv[0] = L0*inv; rv[1] = L1*inv; rv[2] = L2*inv;
      rv[3] = L3*inv; rv[4] = L4*inv; rv[5] = L5*inv;
    }
#pragma unroll
    for (int a = 0; a < 6; ++a)
#pragma unroll
      for (int c2 = 0; c2 < 6; ++c2)
        Mp[a * 6 + c2] = fmaf(jv[a], jv[c2], Mp[a * 6 + c2]);   // inclusive at t
    float s6[6];
#pragma unroll
    for (int jj = 0; jj < 6; ++jj) {
      float s = 0.f;
#pragma unroll
      for (int a = 0; a < 6; ++a) s = fmaf(rv[a], Mp[a * 6 + jj], s);
      s6[jj] = s;
    }
    unsigned short hh[6], ll[6];
#pragma unroll
    for (int i = 0; i < 6; ++i) hl_split(s6[i], hh[i], ll[i]);
    unsigned* ob = rdMpk + (((size_t)bh * T_ + t) << 4);
    const unsigned h01 = hh[0] | ((unsigned)hh[1] << 16);
    const unsigned h23 = hh[2] | ((unsigned)hh[3] << 16);
    const unsigned h45 = hh[4] | ((unsigned)hh[5] << 16);
    ob[0] = h01; ob[1] = h23; ob[2] = h45;
    ob[3] = h01; ob[4] = h23; ob[5] = h45;
    ob[6] = ll[0] | ((unsigned)ll[1] << 16);
    ob[7] = ll[2] | ((unsigned)ll[3] << 16);
    ob[8] = ll[4] | ((unsigned)ll[5] << 16);
#pragma unroll
    for (int i = 9; i < 16; ++i) ob[i] = 0;
  }
}

// ===== MFMA flash attention: cooperative dbuf K+V LDS staging + defer-max =====
__global__ __launch_bounds__(256) void attn_mfma(
    const float* __restrict__ qkvp,
    const unsigned* __restrict__ Jwpk,
    const unsigned* __restrict__ rdMpk,
    const float* __restrict__ bias_scale,
    float* __restrict__ attnout)
{
  __shared__ __align__(16) unsigned char smem[40960];
  unsigned char* KT = smem;              // 2 x 8192
  unsigned char* VT = smem + 16384;      // 2 x 8192
  unsigned char* PB = smem + 32768;      // 8192

  const int gid = blockIdx.x;
  const int bh = gid & 31;
  const int c = (gid < 256) ? (15 - (gid >> 5)) : ((gid - 256) >> 5);  // LPT
  const int b = bh >> 4, h = bh & 15;
  const int tid = threadIdx.x;
  const int w = tid >> 6;
  const int lane = tid & 63;
  const int lr = lane & 15;
  const int g = lane >> 4;
  const int t0 = c * 64;
  const int nT = c + 1;

  const float* Rows = qkvp + (size_t)b * T_ * NA_ + h * 64;
  const size_t jb = (size_t)(b * H_ + h) * T_;

  bf16x8 qa[2];
  {
    const float* qp = Rows + (size_t)(t0 + w * 16 + lr) * NA_;
#pragma unroll
    for (int kb = 0; kb < 2; ++kb) {
      const float4 f0 = *(const float4*)(qp + kb * 32 + g * 8);
      const float4 f1 = *(const float4*)(qp + kb * 32 + g * 8 + 4);
      union { uint4 u; bf16x8 v; } qq;
      qq.u = make_uint4(bfpack(f0.x, f0.y), bfpack(f0.z, f0.w),
                        bfpack(f1.x, f1.y), bfpack(f1.z, f1.w));
      qa[kb] = qq.v;
    }
  }
  bf16x8 ra = *(const bf16x8*)(rdMpk + ((jb + t0 + w * 16 + lr) << 4) + g * 4);
  const float bsc = bias_scale[h];

  float m[4], lsum[4];
  f32x4 O[4];
  const f32x4 zf = {0.f, 0.f, 0.f, 0.f};
#pragma unroll
  for (int r = 0; r < 4; ++r) { m[r] = -1e30f; lsum[r] = 0.f; }
#pragma unroll
  for (int d = 0; d < 4; ++d) O[d] = zf;

  const int kr = tid >> 2, kc = tid & 3;
  const int sp = tid & 31, d8 = tid >> 5;

  float4 kA[4], vA0, vA1, vA2, vA3, kN[4], vN0, vN1, vN2, vN3;
  {
    const float* kp = Rows + (size_t)kr * NA_ + 1024 + kc * 16;
#pragma unroll
    for (int i = 0; i < 4; ++i) kA[i] = *(const float4*)(kp + i * 4);
    const float* vr = Rows + (size_t)(2 * sp) * NA_ + 2048 + d8 * 8;
    vA0 = *(const float4*)vr;         vA1 = *(const float4*)(vr + 4);
    vA2 = *(const float4*)(vr + NA_); vA3 = *(const float4*)(vr + NA_ + 4);
  }

  for (int ti = 0; ti < nT; ++ti) {
    const int s0 = ti * 64;
    const int buf = ti & 1;
    {
      unsigned char* kt = KT + buf * 8192;
      const float e[16] = {kA[0].x, kA[0].y, kA[0].z, kA[0].w,
                           kA[1].x, kA[1].y, kA[1].z, kA[1].w,
                           kA[2].x, kA[2].y, kA[2].z, kA[2].w,
                           kA[3].x, kA[3].y, kA[3].z, kA[3].w};
      const int swz = (kr & 7) << 4;
      uint4 w0, w1;
      w0.x = bfpack(e[0], e[1]);  w0.y = bfpack(e[2], e[3]);
      w0.z = bfpack(e[4], e[5]);  w0.w = bfpack(e[6], e[7]);
      w1.x = bfpack(e[8], e[9]);  w1.y = bfpack(e[10], e[11]);
      w1.z = bfpack(e[12], e[13]); w1.w = bfpack(e[14], e[15]);
      *(uint4*)(kt + kr * 128 + ((kc * 32) ^ swz))      = w0;
      *(uint4*)(kt + kr * 128 + ((kc * 32 + 16) ^ swz)) = w1;
    }
    {
      unsigned* vt = (unsigned*)(VT + buf * 8192);
      const float r0[8] = {vA0.x, vA0.y, vA0.z, vA0.w, vA1.x, vA1.y, vA1.z, vA1.w};
      const float r1[8] = {vA2.x, vA2.y, vA2.z, vA2.w, vA3.x, vA3.y, vA3.z, vA3.w};
#pragma unroll
      for (int i = 0; i < 8; ++i) {
        const int d = d8 * 8 + i;
        vt[d * 32 + (sp ^ ((d & 7) << 2))] = bfpack(r0[i], r1[i]);
      }
    }
    if (ti + 1 < nT) {
      const float* kp = Rows + (size_t)(s0 + 64 + kr) * NA_ + 1024 + kc * 16;
#pragma unroll
      for (int i = 0; i < 4; ++i) kN[i] = *(const float4*)(kp + i * 4);
      const float* vr = Rows + (size_t)(s0 + 64 + 2 * sp) * NA_ + 2048 + d8 * 8;
      vN0 = *(const float4*)vr;         vN1 = *(const float4*)(vr + 4);
      vN2 = *(const float4*)(vr + NA_); vN3 = *(const float4*)(vr + NA_ + 4);
    }
    __syncthreads();

    f32x4 S[4], Sb[4];
    const unsigned char* kt = KT + buf * 8192;
    __builtin_amdgcn_s_setprio(1);
#pragma unroll
    for (int cb = 0; cb < 4; ++cb) {
      const int srw = cb * 16 + lr;
      f32x4 a = zf;
#pragma unroll
      for (int kb = 0; kb < 2; ++kb) {
        const bf16x8 kf = *(const bf16x8*)(kt + srw * 128 + (((kb * 64) + 16 * g) ^ ((srw & 7) << 4)));
        a = __builtin_amdgcn_mfma_f32_16x16x32_bf16(qa[kb], kf, a, 0, 0, 0);
      }
      S[cb] = a;
      const bf16x8 jw = *(const bf16x8*)(Jwpk + ((jb + s0 + cb * 16 + lr) << 4) + g * 4);
      Sb[cb] = __builtin_amdgcn_mfma_f32_16x16x32_bf16(ra, jw, zf, 0, 0, 0);
    }
    __builtin_amdgcn_s_setprio(0);

    const bool diag = (s0 == t0);
    float logit[4][4];
#pragma unroll
    for (int cb = 0; cb < 4; ++cb) {
#pragma unroll
      for (int r = 0; r < 4; ++r) {
        float lg = S[cb][r] * 0.125f + fabsf(Sb[cb][r]) * bsc;
        if (diag && (cb * 16 + lr > w * 16 + 4 * g + r)) lg = -1e30f;
        logit[cb][r] = lg;
      }
    }
    // per-row tile max
    float mxr[4];
#pragma unroll
    for (int r = 0; r < 4; ++r) {
      float mx = fmaxf(fmaxf(logit[0][r], logit[1][r]), fmaxf(logit[2][r], logit[3][r]));
      mx = fmaxf(mx, __shfl_xor(mx, 1));
      mx = fmaxf(mx, __shfl_xor(mx, 2));
      mx = fmaxf(mx, __shfl_xor(mx, 4));
      mx = fmaxf(mx, __shfl_xor(mx, 8));
      mxr[r] = mx;
    }
    // defer-max (T13): rescale only when a row's max grew past threshold
    bool need = false;
#pragma unroll
    for (int r = 0; r < 4; ++r) need = need || (mxr[r] > m[r] + 8.f);
    if (__any(need)) {
#pragma unroll
      for (int r = 0; r < 4; ++r) {
        const float nm = fmaxf(m[r], mxr[r]);
        const float sc = __expf(m[r] - nm);
        m[r] = nm;
        lsum[r] *= sc;
#pragma unroll
        for (int d = 0; d < 4; ++d) O[d][r] *= sc;
      }
    }
#pragma unroll
    for (int cb = 0; cb < 4; ++cb) {
#pragma unroll
      for (int r = 0; r < 4; ++r) {
        const float p = __expf(logit[cb][r] - m[r]);
        lsum[r] += p;
        const int q = 4 * g + r;
        const int s = cb * 16 + lr;
        const int byte = w * 2048 + q * 128 + ((2 * s) ^ ((q & 7) << 4));
        *(unsigned short*)(PB + byte) = f2bf(p);
      }
    }
    asm volatile("s_waitcnt lgkmcnt(0)" ::: "memory");
    __builtin_amdgcn_sched_barrier(0);

    bf16x8 pa[2];
#pragma unroll
    for (int kb = 0; kb < 2; ++kb) {
      const int byte = w * 2048 + lr * 128 + (((kb * 64) + 16 * g) ^ ((lr & 7) << 4));
      pa[kb] = *(const bf16x8*)(PB + byte);
    }
    const unsigned char* vtb = VT + buf * 8192;
    __builtin_amdgcn_s_setprio(1);
#pragma unroll
    for (int db = 0; db < 4; ++db) {
      const int d = db * 16 + lr;
#pragma unroll
      for (int kb = 0; kb < 2; ++kb) {
        const int byte = d * 128 + (((kb * 64) + 16 * g) ^ ((d & 7) << 4));
        const bf16x8 vf = *(const bf16x8*)(vtb + byte);
        O[db] = __builtin_amdgcn_mfma_f32_16x16x32_bf16(pa[kb], vf, O[db], 0, 0, 0);
      }
    }
    __builtin_amdgcn_s_setprio(0);
#pragma unroll
    for (int i = 0; i < 4; ++i) kA[i] = kN[i];
    vA0 = vN0; vA1 = vN1; vA2 = vN2; vA3 = vN3;
  }

#pragma unroll
  for (int r = 0; r < 4; ++r) {
    float l = lsum[r];
    l += __shfl_xor(l, 1);
    l += __shfl_xor(l, 2);
    l += __shfl_xor(l, 4);
    l += __shfl_xor(l, 8);
    lsum[r] = 1.f / l;
  }
  {
    const int qb = w * 16 + 4 * g;
#pragma unroll
    for (int db = 0; db < 4; ++db) {
#pragma unroll
      for (int r = 0; r < 4; ++r) {
        const int t = t0 + qb + r;
        attnout[(size_t)(b * T_ + t) * 1024 + h * 64 + db * 16 + lr] = O[db][r] * lsum[r];
      }
    }
  }
}

// =============================== launcher ===============================
extern "C" void kernel_launch(void* const* d_in, const int* in_sizes, int n_in,
                              void* d_out, int out_size, void* d_ws, size_t ws_size,
                              hipStream_t stream)
{
  (void)in_sizes; (void)n_in; (void)out_size; (void)ws_size;
  const float* x    = (const float*)d_in[0];
  const float* Wqkv = (const float*)d_in[1];
  const float* bqkv = (const float*)d_in[2];
  const float* W1w  = (const float*)d_in[3];
  const float* W2w  = (const float*)d_in[4];
  const float* W1r  = (const float*)d_in[5];
  const float* W2r  = (const float*)d_in[6];
  const float* bsc  = (const float*)d_in[7];
  const float* Wout = (const float*)d_in[8];
  const float* bout = (const float*)d_in[9];
  float* out = (float*)d_out;

  float*    qkvp    = (float*)d_ws;                     // 2048*3328 f
  unsigned* Jwpk    = (unsigned*)(qkvp + (size_t)2048 * NA_);  // 524288 u32
  unsigned* rdMpk   = Jwpk + 524288;                    // 524288 u32
  float*    attnout = (float*)(rdMpk + 524288);         // 2097152 f

  gemm_qkv<<<dim3(26, 32), 256, 0, stream>>>(
      x, Wqkv, bqkv, W1w, W2w, W1r, W2r, qkvp);
  scan_kernel<<<dim3(B_ * H_), 256, 0, stream>>>(qkvp, Jwpk, rdMpk);
  attn_mfma<<<dim3(B_ * H_ * (T_ / 64)), 256, 0, stream>>>(
      qkvp, Jwpk, rdMpk, bsc, attnout);
  gemm_out<<<dim3(8, 32), 256, 0, stream>>>(attnout, Wout, bout, out);
}

// Round 14
// 133.860 us; speedup vs baseline: 1.4561x; 1.4561x over previous
//
#include <hip/hip_runtime.h>
#include <math.h>

#define B_ 2
#define T_ 1024
#define D_ 1024
#define H_ 16
#define NA_ 3328   // qkvp width: 3*D + 4*64 lines

typedef __attribute__((ext_vector_type(8))) short bf16x8;
typedef __attribute__((ext_vector_type(4))) float f32x4;

__device__ inline unsigned short f2bf(float x) {
  return (unsigned short)((__float_as_uint(x) + 0x8000u) >> 16);
}
// pack two f32 -> dword of 2 bf16 (lo in low half)
__device__ inline unsigned bfpack(float lo, float hi) {
  unsigned a = __float_as_uint(hi) + 0x8000u;
  unsigned b = __float_as_uint(lo) + 0x8000u;
  return __builtin_amdgcn_perm(a, b, 0x07060302);
}
__device__ inline void hl_split(float x, unsigned short& h, unsigned short& l) {
  unsigned short hh = f2bf(x);
  float hf = __uint_as_float(((unsigned)hh) << 16);
  l = f2bf(x - hf);
  h = hh;
}

// ===== bf16 MFMA GEMM core: 128x128 tile, 256 threads (2x2 waves), BK=32, dbuf =====
// f32 global reads, f32->bf16 conversion during staging, slot-major LDS.
// R12-measured: gemm_qkv 50 us, FETCH 59.5 MB, WRITE 26.6 MB (clean).
#define G_PRO()                                                                \
  const int tid = threadIdx.x;                                                 \
  const int w = tid >> 6, lane = tid & 63;                                     \
  const int lr = lane & 15, g = lane >> 4;                                     \
  const int wm = (w >> 1) * 64, wn = (w & 1) * 64;                             \
  const int row = tid >> 1, half = tid & 1;

#define G_LOADA(d, s) {                                                        \
  d[0] = *(const float4*)(Ap + (s) * 32);                                      \
  d[1] = *(const float4*)(Ap + (s) * 32 + 4);                                  \
  d[2] = *(const float4*)(Ap + (s) * 32 + 8);                                  \
  d[3] = *(const float4*)(Ap + (s) * 32 + 12); }
#define G_LOADB(d, s) {                                                        \
  d[0] = *(const float4*)(Bp + (s) * 32);                                      \
  d[1] = *(const float4*)(Bp + (s) * 32 + 4);                                  \
  d[2] = *(const float4*)(Bp + (s) * 32 + 8);                                  \
  d[3] = *(const float4*)(Bp + (s) * 32 + 12); }
#define G_STORE(bi, a, b) {                                                    \
  unsigned char* SA_ = Smem + (bi) * 8192;                                     \
  uint4 lo = make_uint4(bfpack(a[0].x, a[0].y), bfpack(a[0].z, a[0].w),        \
                        bfpack(a[1].x, a[1].y), bfpack(a[1].z, a[1].w));       \
  uint4 hi = make_uint4(bfpack(a[2].x, a[2].y), bfpack(a[2].z, a[2].w),        \
                        bfpack(a[3].x, a[3].y), bfpack(a[3].z, a[3].w));       \
  *(uint4*)(SA_ + (half * 2 + 0) * 2048 + row * 16) = lo;                      \
  *(uint4*)(SA_ + (half * 2 + 1) * 2048 + row * 16) = hi;                      \
  unsigned char* SB_ = Smem + 16384 + (bi) * 8192;                             \
  lo = make_uint4(bfpack(b[0].x, b[0].y), bfpack(b[0].z, b[0].w),              \
                  bfpack(b[1].x, b[1].y), bfpack(b[1].z, b[1].w));             \
  hi = make_uint4(bfpack(b[2].x, b[2].y), bfpack(b[2].z, b[2].w),              \
                  bfpack(b[3].x, b[3].y), bfpack(b[3].z, b[3].w));             \
  *(uint4*)(SB_ + (half * 2 + 0) * 2048 + row * 16) = lo;                      \
  *(uint4*)(SB_ + (half * 2 + 1) * 2048 + row * 16) = hi; }
#define G_COMPUTE(bi) {                                                        \
  const unsigned char* SA_ = Smem + (bi) * 8192;                               \
  const unsigned char* SB_ = Smem + 16384 + (bi) * 8192;                       \
  bf16x8 af[4], bfr[4];                                                        \
  _Pragma("unroll") for (int i = 0; i < 4; ++i)                                \
    af[i] = *(const bf16x8*)(SA_ + g * 2048 + (wm + i * 16 + lr) * 16);        \
  _Pragma("unroll") for (int j = 0; j < 4; ++j)                                \
    bfr[j] = *(const bf16x8*)(SB_ + g * 2048 + (wn + j * 16 + lr) * 16);       \
  _Pragma("unroll") for (int i = 0; i < 4; ++i)                                \
  _Pragma("unroll") for (int j = 0; j < 4; ++j)                                \
    acc[i][j] = __builtin_amdgcn_mfma_f32_16x16x32_bf16(af[i], bfr[j],         \
                                                        acc[i][j], 0, 0, 0); }
#define G_MAIN()                                                               \
  f32x4 acc[4][4];                                                             \
  const f32x4 zf = {0.f, 0.f, 0.f, 0.f};                                       \
  _Pragma("unroll") for (int i = 0; i < 4; ++i)                                \
  _Pragma("unroll") for (int j = 0; j < 4; ++j) acc[i][j] = zf;                \
  float4 a0[4], b0[4], a1[4], b1[4];                                           \
  G_LOADA(a0, 0); G_LOADB(b0, 0);                                              \
  G_STORE(0, a0, b0);                                                          \
  G_LOADA(a1, 1); G_LOADB(b1, 1);                                              \
  __syncthreads();                                                             \
  _Pragma("unroll 1") for (int s = 0; s < 32; s += 2) {                        \
    G_COMPUTE(0);                                                              \
    G_STORE(1, a1, b1);                                                        \
    if (s + 2 < 32) { G_LOADA(a0, s + 2); G_LOADB(b0, s + 2); }                \
    __syncthreads();                                                           \
    G_COMPUTE(1);                                                              \
    if (s + 2 < 32) G_STORE(0, a0, b0);                                        \
    if (s + 3 < 32) { G_LOADA(a1, s + 3); G_LOADB(b1, s + 3); }                \
    __syncthreads();                                                           \
  }

// qkv GEMM: qkvp[2048,3328] f32 = x @ [Wqkv;W1w;W2w;W1r;W2r]^T (+bias cols<3072).
__global__ __launch_bounds__(256) void gemm_qkv(
    const float* __restrict__ A, const float* __restrict__ Wqkv,
    const float* __restrict__ bqkv,
    const float* __restrict__ W1w, const float* __restrict__ W2w,
    const float* __restrict__ W1r, const float* __restrict__ W2r,
    float* __restrict__ C)
{
  __shared__ __align__(16) unsigned char Smem[32768];
  const int m0 = blockIdx.y * 128, n0 = blockIdx.x * 128;
  G_PRO();
  const float* Ap = A + (size_t)(m0 + row) * 1024 + half * 16;
  const float* Bp;
  {
    const int cg = n0 + row;
    if (cg < 3072) Bp = Wqkv + (size_t)cg * 1024;
    else {
      const int r2 = cg - 3072;
      const float* Wm = (r2 < 64) ? W1w : (r2 < 128) ? W2w : (r2 < 192) ? W1r : W2r;
      Bp = Wm + (size_t)(r2 & 63) * 1024;
    }
    Bp += half * 16;
  }
  G_MAIN();
#pragma unroll
  for (int i = 0; i < 4; ++i) {
    const int rbase = m0 + wm + i * 16 + 4 * g;
#pragma unroll
    for (int j = 0; j < 4; ++j) {
      const int col = n0 + wn + j * 16 + lr;
      const float bb = (col < 3072) ? bqkv[col] : 0.f;
#pragma unroll
      for (int r = 0; r < 4; ++r)
        C[(size_t)(rbase + r) * NA_ + col] = acc[i][j][r] + bb;
    }
  }
}

// out GEMM: out[2048,1024] f32 = attnout @ Wout^T + bout
__global__ __launch_bounds__(256) void gemm_out(
    const float* __restrict__ A, const float* __restrict__ Bm,
    const float* __restrict__ bias, float* __restrict__ C)
{
  __shared__ __align__(16) unsigned char Smem[32768];
  const int m0 = blockIdx.y * 128, n0 = blockIdx.x * 128;
  G_PRO();
  const float* Ap = A + (size_t)(m0 + row) * 1024 + half * 16;
  const float* Bp = Bm + (size_t)(n0 + row) * 1024 + half * 16;
  G_MAIN();
#pragma unroll
  for (int i = 0; i < 4; ++i) {
    const int rbase = m0 + wm + i * 16 + 4 * g;
#pragma unroll
    for (int j = 0; j < 4; ++j) {
      const int col = n0 + wn + j * 16 + lr;
      const float bb = bias[col];
#pragma unroll
      for (int r = 0; r < 4; ++r)
        C[(size_t)(rbase + r) * 1024 + col] = acc[i][j][r] + bb;
    }
  }
}

// ===== fused exterior + causal 6x6 Gram cumsum (Hillis-Steele) -> Jwpk, rdMpk =====
__global__ __launch_bounds__(256) void scan_kernel(
    const float* __restrict__ qkvp,
    unsigned* __restrict__ Jwpk, unsigned* __restrict__ rdMpk)
{
  __shared__ float sc[256][41];   // 41-f32 rows: gcd(41,32)=1 -> spread banks
  const int tid = threadIdx.x;
  const int bh = blockIdx.x;
  const int b = bh >> 4, h = bh & 15;
  const int t0 = tid * 4;

  float L[36];
#pragma unroll
  for (int i = 0; i < 36; ++i) L[i] = 0.f;

  // ---- phase A: write-lines -> Jwpk + local Gram sum L ----
  for (int tt = 0; tt < 4; ++tt) {
    const int t = t0 + tt;
    const size_t rowt = ((size_t)(b * T_) + t) * NA_;
    float4 p1w = make_float4(0.f, 0.f, 0.f, 0.f);
    if (t > 0) p1w = *(const float4*)(qkvp + rowt - NA_ + 3072 + h * 4);
    const float4 p2w = *(const float4*)(qkvp + rowt + 3136 + h * 4);
    const float L0 = p1w.x * p2w.y - p1w.y * p2w.x;
    const float L1 = p1w.x * p2w.z - p1w.z * p2w.x;
    const float L2 = p1w.x * p2w.w - p1w.w * p2w.x;
    const float L3 = p1w.y * p2w.z - p1w.z * p2w.y;
    const float L4 = p1w.y * p2w.w - p1w.w * p2w.y;
    const float L5 = p1w.z * p2w.w - p1w.w * p2w.z;
    const float n = sqrtf(L0 * L0 + L1 * L1 + L2 * L2 + L3 * L3 + L4 * L4 + L5 * L5);
    const float inv = 1.f / fmaxf(n, 1e-12f);
    const float jv[6] = {L5 * inv, -L4 * inv, L3 * inv, L2 * inv, -L1 * inv, L0 * inv};
    unsigned short JH[6], JL[6];
#pragma unroll
    for (int k = 0; k < 6; ++k) hl_split(jv[k], JH[k], JL[k]);
    unsigned* jp = Jwpk + (((size_t)bh * T_ + t) << 4);
    const unsigned h01 = JH[0] | ((unsigned)JH[1] << 16);
    const unsigned h23 = JH[2] | ((unsigned)JH[3] << 16);
    const unsigned h45 = JH[4] | ((unsigned)JH[5] << 16);
    jp[0] = h01; jp[1] = h23; jp[2] = h45;
    jp[3] = JL[0] | ((unsigned)JL[1] << 16);
    jp[4] = JL[2] | ((unsigned)JL[3] << 16);
    jp[5] = JL[4] | ((unsigned)JL[5] << 16);
    jp[6] = h01; jp[7] = h23; jp[8] = h45;
#pragma unroll
    for (int k = 9; k < 16; ++k) jp[k] = 0;
#pragma unroll
    for (int a = 0; a < 6; ++a)
#pragma unroll
      for (int c2 = 0; c2 < 6; ++c2)
        L[a * 6 + c2] = fmaf(jv[a], jv[c2], L[a * 6 + c2]);
  }

  // ---- Hillis-Steele inclusive scan of 36-element Gram blocks ----
  float M[36];
#pragma unroll
  for (int i = 0; i < 36; ++i) M[i] = L[i];
#pragma unroll
  for (int k = 0; k < 9; ++k)
    *(float4*)&sc[tid][k * 4] = make_float4(M[k*4], M[k*4+1], M[k*4+2], M[k*4+3]);
  __syncthreads();
  for (int off = 1; off < 256; off <<= 1) {
    float4 tmp[9];
    const bool act = (tid >= off);
    if (act) {
#pragma unroll
      for (int k = 0; k < 9; ++k) tmp[k] = *(const float4*)&sc[tid - off][k * 4];
    }
    __syncthreads();
    if (act) {
#pragma unroll
      for (int k = 0; k < 9; ++k) {
        M[k*4]   += tmp[k].x; M[k*4+1] += tmp[k].y;
        M[k*4+2] += tmp[k].z; M[k*4+3] += tmp[k].w;
      }
#pragma unroll
      for (int k = 0; k < 9; ++k)
        *(float4*)&sc[tid][k * 4] = make_float4(M[k*4], M[k*4+1], M[k*4+2], M[k*4+3]);
    }
    __syncthreads();
  }

  float Mp[36];
#pragma unroll
  for (int i = 0; i < 36; ++i) Mp[i] = M[i] - L[i];   // exclusive prefix

  // ---- phase B: recompute lines, advance Mp, rd_M -> rdMpk ----
  for (int tt = 0; tt < 4; ++tt) {
    const int t = t0 + tt;
    const size_t rowt = ((size_t)(b * T_) + t) * NA_;
    float4 p1w = make_float4(0.f, 0.f, 0.f, 0.f);
    if (t > 0) p1w = *(const float4*)(qkvp + rowt - NA_ + 3072 + h * 4);
    const float4 p2w = *(const float4*)(qkvp + rowt + 3136 + h * 4);
    const float4 p1r = *(const float4*)(qkvp + rowt + 3200 + h * 4);
    const float4 p2r = *(const float4*)(qkvp + rowt + 3264 + h * 4);
    float jv[6], rv[6];
    {
      const float L0 = p1w.x * p2w.y - p1w.y * p2w.x;
      const float L1 = p1w.x * p2w.z - p1w.z * p2w.x;
      const float L2 = p1w.x * p2w.w - p1w.w * p2w.x;
      const float L3 = p1w.y * p2w.z - p1w.z * p2w.y;
      const float L4 = p1w.y * p2w.w - p1w.w * p2w.y;
      const float L5 = p1w.z * p2w.w - p1w.w * p2w.z;
      const float n = sqrtf(L0*L0 + L1*L1 + L2*L2 + L3*L3 + L4*L4 + L5*L5);
      const float inv = 1.f / fmaxf(n, 1e-12f);
      jv[0] = L5*inv; jv[1] = -L4*inv; jv[2] = L3*inv;
      jv[3] = L2*inv; jv[4] = -L1*inv; jv[5] = L0*inv;
    }
    {
      const float L0 = p1r.x * p2r.y - p1r.y * p2r.x;
      const float L1 = p1r.x * p2r.z - p1r.z * p2r.x;
      const float L2 = p1r.x * p2r.w - p1r.w * p2r.x;
      const float L3 = p1r.y * p2r.z - p1r.z * p2r.y;
      const float L4 = p1r.y * p2r.w - p1r.w * p2r.y;
      const float L5 = p1r.z * p2r.w - p1r.w * p2r.z;
      const float n = sqrtf(L0*L0 + L1*L1 + L2*L2 + L3*L3 + L4*L4 + L5*L5);
      const float inv = 1.f / fmaxf(n, 1e-12f);
      rv[0] = L0*inv; rv[1] = L1*inv; rv[2] = L2*inv;
      rv[3] = L3*inv; rv[4] = L4*inv; rv[5] = L5*inv;
    }
#pragma unroll
    for (int a = 0; a < 6; ++a)
#pragma unroll
      for (int c2 = 0; c2 < 6; ++c2)
        Mp[a * 6 + c2] = fmaf(jv[a], jv[c2], Mp[a * 6 + c2]);   // inclusive at t
    float s6[6];
#pragma unroll
    for (int jj = 0; jj < 6; ++jj) {
      float s = 0.f;
#pragma unroll
      for (int a = 0; a < 6; ++a) s = fmaf(rv[a], Mp[a * 6 + jj], s);
      s6[jj] = s;
    }
    unsigned short hh[6], ll[6];
#pragma unroll
    for (int i = 0; i < 6; ++i) hl_split(s6[i], hh[i], ll[i]);
    unsigned* ob = rdMpk + (((size_t)bh * T_ + t) << 4);
    const unsigned h01 = hh[0] | ((unsigned)hh[1] << 16);
    const unsigned h23 = hh[2] | ((unsigned)hh[3] << 16);
    const unsigned h45 = hh[4] | ((unsigned)hh[5] << 16);
    ob[0] = h01; ob[1] = h23; ob[2] = h45;
    ob[3] = h01; ob[4] = h23; ob[5] = h45;
    ob[6] = ll[0] | ((unsigned)ll[1] << 16);
    ob[7] = ll[2] | ((unsigned)ll[3] << 16);
    ob[8] = ll[4] | ((unsigned)ll[5] << 16);
#pragma unroll
    for (int i = 9; i < 16; ++i) ob[i] = 0;
  }
}

// ===== MFMA flash attention: cooperative dbuf K+V LDS staging + defer-max =====
__global__ __launch_bounds__(256) void attn_mfma(
    const float* __restrict__ qkvp,
    const unsigned* __restrict__ Jwpk,
    const unsigned* __restrict__ rdMpk,
    const float* __restrict__ bias_scale,
    float* __restrict__ attnout)
{
  __shared__ __align__(16) unsigned char smem[40960];
  unsigned char* KT = smem;              // 2 x 8192
  unsigned char* VT = smem + 16384;      // 2 x 8192
  unsigned char* PB = smem + 32768;      // 8192

  const int gid = blockIdx.x;
  const int bh = gid & 31;
  const int c = (gid < 256) ? (15 - (gid >> 5)) : ((gid - 256) >> 5);  // LPT
  const int b = bh >> 4, h = bh & 15;
  const int tid = threadIdx.x;
  const int w = tid >> 6;
  const int lane = tid & 63;
  const int lr = lane & 15;
  const int g = lane >> 4;
  const int t0 = c * 64;
  const int nT = c + 1;

  const float* Rows = qkvp + (size_t)b * T_ * NA_ + h * 64;
  const size_t jb = (size_t)(b * H_ + h) * T_;

  bf16x8 qa[2];
  {
    const float* qp = Rows + (size_t)(t0 + w * 16 + lr) * NA_;
#pragma unroll
    for (int kb = 0; kb < 2; ++kb) {
      const float4 f0 = *(const float4*)(qp + kb * 32 + g * 8);
      const float4 f1 = *(const float4*)(qp + kb * 32 + g * 8 + 4);
      union { uint4 u; bf16x8 v; } qq;
      qq.u = make_uint4(bfpack(f0.x, f0.y), bfpack(f0.z, f0.w),
                        bfpack(f1.x, f1.y), bfpack(f1.z, f1.w));
      qa[kb] = qq.v;
    }
  }
  bf16x8 ra = *(const bf16x8*)(rdMpk + ((jb + t0 + w * 16 + lr) << 4) + g * 4);
  const float bsc = bias_scale[h];

  float m[4], lsum[4];
  f32x4 O[4];
  const f32x4 zf = {0.f, 0.f, 0.f, 0.f};
#pragma unroll
  for (int r = 0; r < 4; ++r) { m[r] = -1e30f; lsum[r] = 0.f; }
#pragma unroll
  for (int d = 0; d < 4; ++d) O[d] = zf;

  const int kr = tid >> 2, kc = tid & 3;
  const int sp = tid & 31, d8 = tid >> 5;

  float4 kA[4], vA0, vA1, vA2, vA3, kN[4], vN0, vN1, vN2, vN3;
  {
    const float* kp = Rows + (size_t)kr * NA_ + 1024 + kc * 16;
#pragma unroll
    for (int i = 0; i < 4; ++i) kA[i] = *(const float4*)(kp + i * 4);
    const float* vr = Rows + (size_t)(2 * sp) * NA_ + 2048 + d8 * 8;
    vA0 = *(const float4*)vr;         vA1 = *(const float4*)(vr + 4);
    vA2 = *(const float4*)(vr + NA_); vA3 = *(const float4*)(vr + NA_ + 4);
  }

  for (int ti = 0; ti < nT; ++ti) {
    const int s0 = ti * 64;
    const int buf = ti & 1;
    {
      unsigned char* kt = KT + buf * 8192;
      const float e[16] = {kA[0].x, kA[0].y, kA[0].z, kA[0].w,
                           kA[1].x, kA[1].y, kA[1].z, kA[1].w,
                           kA[2].x, kA[2].y, kA[2].z, kA[2].w,
                           kA[3].x, kA[3].y, kA[3].z, kA[3].w};
      const int swz = (kr & 7) << 4;
      uint4 w0, w1;
      w0.x = bfpack(e[0], e[1]);  w0.y = bfpack(e[2], e[3]);
      w0.z = bfpack(e[4], e[5]);  w0.w = bfpack(e[6], e[7]);
      w1.x = bfpack(e[8], e[9]);  w1.y = bfpack(e[10], e[11]);
      w1.z = bfpack(e[12], e[13]); w1.w = bfpack(e[14], e[15]);
      *(uint4*)(kt + kr * 128 + ((kc * 32) ^ swz))      = w0;
      *(uint4*)(kt + kr * 128 + ((kc * 32 + 16) ^ swz)) = w1;
    }
    {
      unsigned* vt = (unsigned*)(VT + buf * 8192);
      const float r0[8] = {vA0.x, vA0.y, vA0.z, vA0.w, vA1.x, vA1.y, vA1.z, vA1.w};
      const float r1[8] = {vA2.x, vA2.y, vA2.z, vA2.w, vA3.x, vA3.y, vA3.z, vA3.w};
#pragma unroll
      for (int i = 0; i < 8; ++i) {
        const int d = d8 * 8 + i;
        vt[d * 32 + (sp ^ ((d & 7) << 2))] = bfpack(r0[i], r1[i]);
      }
    }
    if (ti + 1 < nT) {
      const float* kp = Rows + (size_t)(s0 + 64 + kr) * NA_ + 1024 + kc * 16;
#pragma unroll
      for (int i = 0; i < 4; ++i) kN[i] = *(const float4*)(kp + i * 4);
      const float* vr = Rows + (size_t)(s0 + 64 + 2 * sp) * NA_ + 2048 + d8 * 8;
      vN0 = *(const float4*)vr;         vN1 = *(const float4*)(vr + 4);
      vN2 = *(const float4*)(vr + NA_); vN3 = *(const float4*)(vr + NA_ + 4);
    }
    __syncthreads();

    f32x4 S[4], Sb[4];
    const unsigned char* kt = KT + buf * 8192;
    __builtin_amdgcn_s_setprio(1);
#pragma unroll
    for (int cb = 0; cb < 4; ++cb) {
      const int srw = cb * 16 + lr;
      f32x4 a = zf;
#pragma unroll
      for (int kb = 0; kb < 2; ++kb) {
        const bf16x8 kf = *(const bf16x8*)(kt + srw * 128 + (((kb * 64) + 16 * g) ^ ((srw & 7) << 4)));
        a = __builtin_amdgcn_mfma_f32_16x16x32_bf16(qa[kb], kf, a, 0, 0, 0);
      }
      S[cb] = a;
      const bf16x8 jw = *(const bf16x8*)(Jwpk + ((jb + s0 + cb * 16 + lr) << 4) + g * 4);
      Sb[cb] = __builtin_amdgcn_mfma_f32_16x16x32_bf16(ra, jw, zf, 0, 0, 0);
    }
    __builtin_amdgcn_s_setprio(0);

    const bool diag = (s0 == t0);
    float logit[4][4];
#pragma unroll
    for (int cb = 0; cb < 4; ++cb) {
#pragma unroll
      for (int r = 0; r < 4; ++r) {
        float lg = S[cb][r] * 0.125f + fabsf(Sb[cb][r]) * bsc;
        if (diag && (cb * 16 + lr > w * 16 + 4 * g + r)) lg = -1e30f;
        logit[cb][r] = lg;
      }
    }
    float mxr[4];
#pragma unroll
    for (int r = 0; r < 4; ++r) {
      float mx = fmaxf(fmaxf(logit[0][r], logit[1][r]), fmaxf(logit[2][r], logit[3][r]));
      mx = fmaxf(mx, __shfl_xor(mx, 1));
      mx = fmaxf(mx, __shfl_xor(mx, 2));
      mx = fmaxf(mx, __shfl_xor(mx, 4));
      mx = fmaxf(mx, __shfl_xor(mx, 8));
      mxr[r] = mx;
    }
    // defer-max (T13): rescale only when a row's max grew past threshold
    bool need = false;
#pragma unroll
    for (int r = 0; r < 4; ++r) need = need || (mxr[r] > m[r] + 8.f);
    if (__any(need)) {
#pragma unroll
      for (int r = 0; r < 4; ++r) {
        const float nm = fmaxf(m[r], mxr[r]);
        const float sc = __expf(m[r] - nm);
        m[r] = nm;
        lsum[r] *= sc;
#pragma unroll
        for (int d = 0; d < 4; ++d) O[d][r] *= sc;
      }
    }
#pragma unroll
    for (int cb = 0; cb < 4; ++cb) {
#pragma unroll
      for (int r = 0; r < 4; ++r) {
        const float p = __expf(logit[cb][r] - m[r]);
        lsum[r] += p;
        const int q = 4 * g + r;
        const int s = cb * 16 + lr;
        const int byte = w * 2048 + q * 128 + ((2 * s) ^ ((q & 7) << 4));
        *(unsigned short*)(PB + byte) = f2bf(p);
      }
    }
    asm volatile("s_waitcnt lgkmcnt(0)" ::: "memory");
    __builtin_amdgcn_sched_barrier(0);

    bf16x8 pa[2];
#pragma unroll
    for (int kb = 0; kb < 2; ++kb) {
      const int byte = w * 2048 + lr * 128 + (((kb * 64) + 16 * g) ^ ((lr & 7) << 4));
      pa[kb] = *(const bf16x8*)(PB + byte);
    }
    const unsigned char* vtb = VT + buf * 8192;
    __builtin_amdgcn_s_setprio(1);
#pragma unroll
    for (int db = 0; db < 4; ++db) {
      const int d = db * 16 + lr;
#pragma unroll
      for (int kb = 0; kb < 2; ++kb) {
        const int byte = d * 128 + (((kb * 64) + 16 * g) ^ ((d & 7) << 4));
        const bf16x8 vf = *(const bf16x8*)(vtb + byte);
        O[db] = __builtin_amdgcn_mfma_f32_16x16x32_bf16(pa[kb], vf, O[db], 0, 0, 0);
      }
    }
    __builtin_amdgcn_s_setprio(0);
#pragma unroll
    for (int i = 0; i < 4; ++i) kA[i] = kN[i];
    vA0 = vN0; vA1 = vN1; vA2 = vN2; vA3 = vN3;
  }

#pragma unroll
  for (int r = 0; r < 4; ++r) {
    float l = lsum[r];
    l += __shfl_xor(l, 1);
    l += __shfl_xor(l, 2);
    l += __shfl_xor(l, 4);
    l += __shfl_xor(l, 8);
    lsum[r] = 1.f / l;
  }
  {
    const int qb = w * 16 + 4 * g;
#pragma unroll
    for (int db = 0; db < 4; ++db) {
#pragma unroll
      for (int r = 0; r < 4; ++r) {
        const int t = t0 + qb + r;
        attnout[(size_t)(b * T_ + t) * 1024 + h * 64 + db * 16 + lr] = O[db][r] * lsum[r];
      }
    }
  }
}

// =============================== launcher ===============================
extern "C" void kernel_launch(void* const* d_in, const int* in_sizes, int n_in,
                              void* d_out, int out_size, void* d_ws, size_t ws_size,
                              hipStream_t stream)
{
  (void)in_sizes; (void)n_in; (void)out_size; (void)ws_size;
  const float* x    = (const float*)d_in[0];
  const float* Wqkv = (const float*)d_in[1];
  const float* bqkv = (const float*)d_in[2];
  const float* W1w  = (const float*)d_in[3];
  const float* W2w  = (const float*)d_in[4];
  const float* W1r  = (const float*)d_in[5];
  const float* W2r  = (const float*)d_in[6];
  const float* bsc  = (const float*)d_in[7];
  const float* Wout = (const float*)d_in[8];
  const float* bout = (const float*)d_in[9];
  float* out = (float*)d_out;

  float*    qkvp    = (float*)d_ws;                     // 2048*3328 f
  unsigned* Jwpk    = (unsigned*)(qkvp + (size_t)2048 * NA_);  // 524288 u32
  unsigned* rdMpk   = Jwpk + 524288;                    // 524288 u32
  float*    attnout = (float*)(rdMpk + 524288);         // 2097152 f

  gemm_qkv<<<dim3(26, 16), 256, 0, stream>>>(
      x, Wqkv, bqkv, W1w, W2w, W1r, W2r, qkvp);
  scan_kernel<<<dim3(B_ * H_), 256, 0, stream>>>(qkvp, Jwpk, rdMpk);
  attn_mfma<<<dim3(B_ * H_ * (T_ / 64)), 256, 0, stream>>>(
      qkvp, Jwpk, rdMpk, bsc, attnout);
  gemm_out<<<dim3(8, 16), 256, 0, stream>>>(attnout, Wout, bout, out);
}

// Round 15
// 115.909 us; speedup vs baseline: 1.6816x; 1.1549x over previous
//
#include <hip/hip_runtime.h>
#include <math.h>

#define B_ 2
#define T_ 1024
#define D_ 1024
#define H_ 16
#define NA_ 3328   // qkvp width: 3*D + 4*64 lines

typedef __attribute__((ext_vector_type(8))) short bf16x8;
typedef __attribute__((ext_vector_type(4))) float f32x4;

__device__ inline unsigned short f2bf(float x) {
  return (unsigned short)((__float_as_uint(x) + 0x8000u) >> 16);
}
// pack two f32 -> dword of 2 bf16 (lo in low half)
__device__ inline unsigned bfpack(float lo, float hi) {
  unsigned a = __float_as_uint(hi) + 0x8000u;
  unsigned b = __float_as_uint(lo) + 0x8000u;
  return __builtin_amdgcn_perm(a, b, 0x07060302);
}
__device__ inline void hl_split(float x, unsigned short& h, unsigned short& l) {
  unsigned short hh = f2bf(x);
  float hf = __uint_as_float(((unsigned)hh) << 16);
  l = f2bf(x - hf);
  h = hh;
}

// ===== bf16 MFMA GEMM core: 128x128 tile, 512 threads (4x2 waves), BK=32, dbuf =====
// f32 global reads, f32->bf16 conversion during staging, slot-major LDS.
// Per wave: 32x64 output = 2x4 16x16 frags. 8 waves/block for latency hiding.
#define G_PRO()                                                                \
  const int tid = threadIdx.x;                                                 \
  const int w = tid >> 6, lane = tid & 63;                                     \
  const int lr = lane & 15, g = lane >> 4;                                     \
  const int wm = (w >> 1) * 32, wn = (w & 1) * 64;                             \
  const int row = tid >> 2, qc = tid & 3;

#define G_LOADA(d, s) {                                                        \
  d[0] = *(const float4*)(Ap + (s) * 32);                                      \
  d[1] = *(const float4*)(Ap + (s) * 32 + 4); }
#define G_LOADB(d, s) {                                                        \
  d[0] = *(const float4*)(Bp + (s) * 32);                                      \
  d[1] = *(const float4*)(Bp + (s) * 32 + 4); }
#define G_STORE(bi, a, b) {                                                    \
  unsigned char* SA_ = Smem + (bi) * 8192;                                     \
  *(uint4*)(SA_ + qc * 2048 + row * 16) =                                      \
      make_uint4(bfpack(a[0].x, a[0].y), bfpack(a[0].z, a[0].w),               \
                 bfpack(a[1].x, a[1].y), bfpack(a[1].z, a[1].w));              \
  unsigned char* SB_ = Smem + 16384 + (bi) * 8192;                             \
  *(uint4*)(SB_ + qc * 2048 + row * 16) =                                      \
      make_uint4(bfpack(b[0].x, b[0].y), bfpack(b[0].z, b[0].w),               \
                 bfpack(b[1].x, b[1].y), bfpack(b[1].z, b[1].w)); }
#define G_COMPUTE(bi) {                                                        \
  const unsigned char* SA_ = Smem + (bi) * 8192;                               \
  const unsigned char* SB_ = Smem + 16384 + (bi) * 8192;                       \
  bf16x8 af[2], bfr[4];                                                        \
  _Pragma("unroll") for (int i = 0; i < 2; ++i)                                \
    af[i] = *(const bf16x8*)(SA_ + g * 2048 + (wm + i * 16 + lr) * 16);        \
  _Pragma("unroll") for (int j = 0; j < 4; ++j)                                \
    bfr[j] = *(const bf16x8*)(SB_ + g * 2048 + (wn + j * 16 + lr) * 16);       \
  _Pragma("unroll") for (int i = 0; i < 2; ++i)                                \
  _Pragma("unroll") for (int j = 0; j < 4; ++j)                                \
    acc[i][j] = __builtin_amdgcn_mfma_f32_16x16x32_bf16(af[i], bfr[j],         \
                                                        acc[i][j], 0, 0, 0); }
#define G_MAIN()                                                               \
  f32x4 acc[2][4];                                                             \
  const f32x4 zf = {0.f, 0.f, 0.f, 0.f};                                       \
  _Pragma("unroll") for (int i = 0; i < 2; ++i)                                \
  _Pragma("unroll") for (int j = 0; j < 4; ++j) acc[i][j] = zf;                \
  float4 a0[2], b0[2], a1[2], b1[2];                                           \
  G_LOADA(a0, 0); G_LOADB(b0, 0);                                              \
  G_STORE(0, a0, b0);                                                          \
  G_LOADA(a1, 1); G_LOADB(b1, 1);                                              \
  __syncthreads();                                                             \
  _Pragma("unroll 1") for (int s = 0; s < 32; s += 2) {                        \
    G_COMPUTE(0);                                                              \
    G_STORE(1, a1, b1);                                                        \
    if (s + 2 < 32) { G_LOADA(a0, s + 2); G_LOADB(b0, s + 2); }                \
    __syncthreads();                                                           \
    G_COMPUTE(1);                                                              \
    if (s + 2 < 32) G_STORE(0, a0, b0);                                        \
    if (s + 3 < 32) { G_LOADA(a1, s + 3); G_LOADB(b1, s + 3); }                \
    __syncthreads();                                                           \
  }

// qkv GEMM: qkvp[2048,3328] f32 = x @ [Wqkv;W1w;W2w;W1r;W2r]^T (+bias cols<3072).
__global__ __launch_bounds__(512) void gemm_qkv(
    const float* __restrict__ A, const float* __restrict__ Wqkv,
    const float* __restrict__ bqkv,
    const float* __restrict__ W1w, const float* __restrict__ W2w,
    const float* __restrict__ W1r, const float* __restrict__ W2r,
    float* __restrict__ C)
{
  __shared__ __align__(16) unsigned char Smem[32768];
  const int m0 = blockIdx.y * 128, n0 = blockIdx.x * 128;
  G_PRO();
  const float* Ap = A + (size_t)(m0 + row) * 1024 + qc * 8;
  const float* Bp;
  {
    const int cg = n0 + row;
    if (cg < 3072) Bp = Wqkv + (size_t)cg * 1024;
    else {
      const int r2 = cg - 3072;
      const float* Wm = (r2 < 64) ? W1w : (r2 < 128) ? W2w : (r2 < 192) ? W1r : W2r;
      Bp = Wm + (size_t)(r2 & 63) * 1024;
    }
    Bp += qc * 8;
  }
  G_MAIN();
#pragma unroll
  for (int i = 0; i < 2; ++i) {
    const int rbase = m0 + wm + i * 16 + 4 * g;
#pragma unroll
    for (int j = 0; j < 4; ++j) {
      const int col = n0 + wn + j * 16 + lr;
      const float bb = (col < 3072) ? bqkv[col] : 0.f;
#pragma unroll
      for (int r = 0; r < 4; ++r)
        C[(size_t)(rbase + r) * NA_ + col] = acc[i][j][r] + bb;
    }
  }
}

// out GEMM: out[2048,1024] f32 = attnout @ Wout^T + bout
__global__ __launch_bounds__(512) void gemm_out(
    const float* __restrict__ A, const float* __restrict__ Bm,
    const float* __restrict__ bias, float* __restrict__ C)
{
  __shared__ __align__(16) unsigned char Smem[32768];
  const int m0 = blockIdx.y * 128, n0 = blockIdx.x * 128;
  G_PRO();
  const float* Ap = A + (size_t)(m0 + row) * 1024 + qc * 8;
  const float* Bp = Bm + (size_t)(n0 + row) * 1024 + qc * 8;
  G_MAIN();
#pragma unroll
  for (int i = 0; i < 2; ++i) {
    const int rbase = m0 + wm + i * 16 + 4 * g;
#pragma unroll
    for (int j = 0; j < 4; ++j) {
      const int col = n0 + wn + j * 16 + lr;
      const float bb = bias[col];
#pragma unroll
      for (int r = 0; r < 4; ++r)
        C[(size_t)(rbase + r) * 1024 + col] = acc[i][j][r] + bb;
    }
  }
}

// ===== fused exterior + causal 6x6 Gram cumsum (Hillis-Steele) -> Jwpk, rdMpk =====
__global__ __launch_bounds__(256) void scan_kernel(
    const float* __restrict__ qkvp,
    unsigned* __restrict__ Jwpk, unsigned* __restrict__ rdMpk)
{
  __shared__ float sc[256][41];   // 41-f32 rows: gcd(41,32)=1 -> spread banks
  const int tid = threadIdx.x;
  const int bh = blockIdx.x;
  const int b = bh >> 4, h = bh & 15;
  const int t0 = tid * 4;

  float L[36];
#pragma unroll
  for (int i = 0; i < 36; ++i) L[i] = 0.f;

  // ---- phase A: write-lines -> Jwpk + local Gram sum L ----
  for (int tt = 0; tt < 4; ++tt) {
    const int t = t0 + tt;
    const size_t rowt = ((size_t)(b * T_) + t) * NA_;
    float4 p1w = make_float4(0.f, 0.f, 0.f, 0.f);
    if (t > 0) p1w = *(const float4*)(qkvp + rowt - NA_ + 3072 + h * 4);
    const float4 p2w = *(const float4*)(qkvp + rowt + 3136 + h * 4);
    const float L0 = p1w.x * p2w.y - p1w.y * p2w.x;
    const float L1 = p1w.x * p2w.z - p1w.z * p2w.x;
    const float L2 = p1w.x * p2w.w - p1w.w * p2w.x;
    const float L3 = p1w.y * p2w.z - p1w.z * p2w.y;
    const float L4 = p1w.y * p2w.w - p1w.w * p2w.y;
    const float L5 = p1w.z * p2w.w - p1w.w * p2w.z;
    const float n = sqrtf(L0 * L0 + L1 * L1 + L2 * L2 + L3 * L3 + L4 * L4 + L5 * L5);
    const float inv = 1.f / fmaxf(n, 1e-12f);
    const float jv[6] = {L5 * inv, -L4 * inv, L3 * inv, L2 * inv, -L1 * inv, L0 * inv};
    unsigned short JH[6], JL[6];
#pragma unroll
    for (int k = 0; k < 6; ++k) hl_split(jv[k], JH[k], JL[k]);
    unsigned* jp = Jwpk + (((size_t)bh * T_ + t) << 4);
    const unsigned h01 = JH[0] | ((unsigned)JH[1] << 16);
    const unsigned h23 = JH[2] | ((unsigned)JH[3] << 16);
    const unsigned h45 = JH[4] | ((unsigned)JH[5] << 16);
    jp[0] = h01; jp[1] = h23; jp[2] = h45;
    jp[3] = JL[0] | ((unsigned)JL[1] << 16);
    jp[4] = JL[2] | ((unsigned)JL[3] << 16);
    jp[5] = JL[4] | ((unsigned)JL[5] << 16);
    jp[6] = h01; jp[7] = h23; jp[8] = h45;
#pragma unroll
    for (int k = 9; k < 16; ++k) jp[k] = 0;
#pragma unroll
    for (int a = 0; a < 6; ++a)
#pragma unroll
      for (int c2 = 0; c2 < 6; ++c2)
        L[a * 6 + c2] = fmaf(jv[a], jv[c2], L[a * 6 + c2]);
  }

  // ---- Hillis-Steele inclusive scan of 36-element Gram blocks ----
  float M[36];
#pragma unroll
  for (int i = 0; i < 36; ++i) M[i] = L[i];
#pragma unroll
  for (int k = 0; k < 9; ++k)
    *(float4*)&sc[tid][k * 4] = make_float4(M[k*4], M[k*4+1], M[k*4+2], M[k*4+3]);
  __syncthreads();
  for (int off = 1; off < 256; off <<= 1) {
    float4 tmp[9];
    const bool act = (tid >= off);
    if (act) {
#pragma unroll
      for (int k = 0; k < 9; ++k) tmp[k] = *(const float4*)&sc[tid - off][k * 4];
    }
    __syncthreads();
    if (act) {
#pragma unroll
      for (int k = 0; k < 9; ++k) {
        M[k*4]   += tmp[k].x; M[k*4+1] += tmp[k].y;
        M[k*4+2] += tmp[k].z; M[k*4+3] += tmp[k].w;
      }
#pragma unroll
      for (int k = 0; k < 9; ++k)
        *(float4*)&sc[tid][k * 4] = make_float4(M[k*4], M[k*4+1], M[k*4+2], M[k*4+3]);
    }
    __syncthreads();
  }

  float Mp[36];
#pragma unroll
  for (int i = 0; i < 36; ++i) Mp[i] = M[i] - L[i];   // exclusive prefix

  // ---- phase B: recompute lines, advance Mp, rd_M -> rdMpk ----
  for (int tt = 0; tt < 4; ++tt) {
    const int t = t0 + tt;
    const size_t rowt = ((size_t)(b * T_) + t) * NA_;
    float4 p1w = make_float4(0.f, 0.f, 0.f, 0.f);
    if (t > 0) p1w = *(const float4*)(qkvp + rowt - NA_ + 3072 + h * 4);
    const float4 p2w = *(const float4*)(qkvp + rowt + 3136 + h * 4);
    const float4 p1r = *(const float4*)(qkvp + rowt + 3200 + h * 4);
    const float4 p2r = *(const float4*)(qkvp + rowt + 3264 + h * 4);
    float jv[6], rv[6];
    {
      const float L0 = p1w.x * p2w.y - p1w.y * p2w.x;
      const float L1 = p1w.x * p2w.z - p1w.z * p2w.x;
      const float L2 = p1w.x * p2w.w - p1w.w * p2w.x;
      const float L3 = p1w.y * p2w.z - p1w.z * p2w.y;
      const float L4 = p1w.y * p2w.w - p1w.w * p2w.y;
      const float L5 = p1w.z * p2w.w - p1w.w * p2w.z;
      const float n = sqrtf(L0*L0 + L1*L1 + L2*L2 + L3*L3 + L4*L4 + L5*L5);
      const float inv = 1.f / fmaxf(n, 1e-12f);
      jv[0] = L5*inv; jv[1] = -L4*inv; jv[2] = L3*inv;
      jv[3] = L2*inv; jv[4] = -L1*inv; jv[5] = L0*inv;
    }
    {
      const float L0 = p1r.x * p2r.y - p1r.y * p2r.x;
      const float L1 = p1r.x * p2r.z - p1r.z * p2r.x;
      const float L2 = p1r.x * p2r.w - p1r.w * p2r.x;
      const float L3 = p1r.y * p2r.z - p1r.z * p2r.y;
      const float L4 = p1r.y * p2r.w - p1r.w * p2r.y;
      const float L5 = p1r.z * p2r.w - p1r.w * p2r.z;
      const float n = sqrtf(L0*L0 + L1*L1 + L2*L2 + L3*L3 + L4*L4 + L5*L5);
      const float inv = 1.f / fmaxf(n, 1e-12f);
      rv[0] = L0*inv; rv[1] = L1*inv; rv[2] = L2*inv;
      rv[3] = L3*inv; rv[4] = L4*inv; rv[5] = L5*inv;
    }
#pragma unroll
    for (int a = 0; a < 6; ++a)
#pragma unroll
      for (int c2 = 0; c2 < 6; ++c2)
        Mp[a * 6 + c2] = fmaf(jv[a], jv[c2], Mp[a * 6 + c2]);   // inclusive at t
    float s6[6];
#pragma unroll
    for (int jj = 0; jj < 6; ++jj) {
      float s = 0.f;
#pragma unroll
      for (int a = 0; a < 6; ++a) s = fmaf(rv[a], Mp[a * 6 + jj], s);
      s6[jj] = s;
    }
    unsigned short hh[6], ll[6];
#pragma unroll
    for (int i = 0; i < 6; ++i) hl_split(s6[i], hh[i], ll[i]);
    unsigned* ob = rdMpk + (((size_t)bh * T_ + t) << 4);
    const unsigned h01 = hh[0] | ((unsigned)hh[1] << 16);
    const unsigned h23 = hh[2] | ((unsigned)hh[3] << 16);
    const unsigned h45 = hh[4] | ((unsigned)hh[5] << 16);
    ob[0] = h01; ob[1] = h23; ob[2] = h45;
    ob[3] = h01; ob[4] = h23; ob[5] = h45;
    ob[6] = ll[0] | ((unsigned)ll[1] << 16);
    ob[7] = ll[2] | ((unsigned)ll[3] << 16);
    ob[8] = ll[4] | ((unsigned)ll[5] << 16);
#pragma unroll
    for (int i = 9; i < 16; ++i) ob[i] = 0;
  }
}

// ===== MFMA flash attention: cooperative dbuf K+V LDS staging + defer-max =====
__global__ __launch_bounds__(256) void attn_mfma(
    const float* __restrict__ qkvp,
    const unsigned* __restrict__ Jwpk,
    const unsigned* __restrict__ rdMpk,
    const float* __restrict__ bias_scale,
    float* __restrict__ attnout)
{
  __shared__ __align__(16) unsigned char smem[40960];
  unsigned char* KT = smem;              // 2 x 8192
  unsigned char* VT = smem + 16384;      // 2 x 8192
  unsigned char* PB = smem + 32768;      // 8192

  const int gid = blockIdx.x;
  const int bh = gid & 31;
  const int c = (gid < 256) ? (15 - (gid >> 5)) : ((gid - 256) >> 5);  // LPT
  const int b = bh >> 4, h = bh & 15;
  const int tid = threadIdx.x;
  const int w = tid >> 6;
  const int lane = tid & 63;
  const int lr = lane & 15;
  const int g = lane >> 4;
  const int t0 = c * 64;
  const int nT = c + 1;

  const float* Rows = qkvp + (size_t)b * T_ * NA_ + h * 64;
  const size_t jb = (size_t)(b * H_ + h) * T_;

  bf16x8 qa[2];
  {
    const float* qp = Rows + (size_t)(t0 + w * 16 + lr) * NA_;
#pragma unroll
    for (int kb = 0; kb < 2; ++kb) {
      const float4 f0 = *(const float4*)(qp + kb * 32 + g * 8);
      const float4 f1 = *(const float4*)(qp + kb * 32 + g * 8 + 4);
      union { uint4 u; bf16x8 v; } qq;
      qq.u = make_uint4(bfpack(f0.x, f0.y), bfpack(f0.z, f0.w),
                        bfpack(f1.x, f1.y), bfpack(f1.z, f1.w));
      qa[kb] = qq.v;
    }
  }
  bf16x8 ra = *(const bf16x8*)(rdMpk + ((jb + t0 + w * 16 + lr) << 4) + g * 4);
  const float bsc = bias_scale[h];

  float m[4], lsum[4];
  f32x4 O[4];
  const f32x4 zf = {0.f, 0.f, 0.f, 0.f};
#pragma unroll
  for (int r = 0; r < 4; ++r) { m[r] = -1e30f; lsum[r] = 0.f; }
#pragma unroll
  for (int d = 0; d < 4; ++d) O[d] = zf;

  const int kr = tid >> 2, kc = tid & 3;
  const int sp = tid & 31, d8 = tid >> 5;

  float4 kA[4], vA0, vA1, vA2, vA3, kN[4], vN0, vN1, vN2, vN3;
  {
    const float* kp = Rows + (size_t)kr * NA_ + 1024 + kc * 16;
#pragma unroll
    for (int i = 0; i < 4; ++i) kA[i] = *(const float4*)(kp + i * 4);
    const float* vr = Rows + (size_t)(2 * sp) * NA_ + 2048 + d8 * 8;
    vA0 = *(const float4*)vr;         vA1 = *(const float4*)(vr + 4);
    vA2 = *(const float4*)(vr + NA_); vA3 = *(const float4*)(vr + NA_ + 4);
  }

  for (int ti = 0; ti < nT; ++ti) {
    const int s0 = ti * 64;
    const int buf = ti & 1;
    {
      unsigned char* kt = KT + buf * 8192;
      const float e[16] = {kA[0].x, kA[0].y, kA[0].z, kA[0].w,
                           kA[1].x, kA[1].y, kA[1].z, kA[1].w,
                           kA[2].x, kA[2].y, kA[2].z, kA[2].w,
                           kA[3].x, kA[3].y, kA[3].z, kA[3].w};
      const int swz = (kr & 7) << 4;
      uint4 w0, w1;
      w0.x = bfpack(e[0], e[1]);  w0.y = bfpack(e[2], e[3]);
      w0.z = bfpack(e[4], e[5]);  w0.w = bfpack(e[6], e[7]);
      w1.x = bfpack(e[8], e[9]);  w1.y = bfpack(e[10], e[11]);
      w1.z = bfpack(e[12], e[13]); w1.w = bfpack(e[14], e[15]);
      *(uint4*)(kt + kr * 128 + ((kc * 32) ^ swz))      = w0;
      *(uint4*)(kt + kr * 128 + ((kc * 32 + 16) ^ swz)) = w1;
    }
    {
      unsigned* vt = (unsigned*)(VT + buf * 8192);
      const float r0[8] = {vA0.x, vA0.y, vA0.z, vA0.w, vA1.x, vA1.y, vA1.z, vA1.w};
      const float r1[8] = {vA2.x, vA2.y, vA2.z, vA2.w, vA3.x, vA3.y, vA3.z, vA3.w};
#pragma unroll
      for (int i = 0; i < 8; ++i) {
        const int d = d8 * 8 + i;
        vt[d * 32 + (sp ^ ((d & 7) << 2))] = bfpack(r0[i], r1[i]);
      }
    }
    if (ti + 1 < nT) {
      const float* kp = Rows + (size_t)(s0 + 64 + kr) * NA_ + 1024 + kc * 16;
#pragma unroll
      for (int i = 0; i < 4; ++i) kN[i] = *(const float4*)(kp + i * 4);
      const float* vr = Rows + (size_t)(s0 + 64 + 2 * sp) * NA_ + 2048 + d8 * 8;
      vN0 = *(const float4*)vr;         vN1 = *(const float4*)(vr + 4);
      vN2 = *(const float4*)(vr + NA_); vN3 = *(const float4*)(vr + NA_ + 4);
    }
    __syncthreads();

    f32x4 S[4], Sb[4];
    const unsigned char* kt = KT + buf * 8192;
    __builtin_amdgcn_s_setprio(1);
#pragma unroll
    for (int cb = 0; cb < 4; ++cb) {
      const int srw = cb * 16 + lr;
      f32x4 a = zf;
#pragma unroll
      for (int kb = 0; kb < 2; ++kb) {
        const bf16x8 kf = *(const bf16x8*)(kt + srw * 128 + (((kb * 64) + 16 * g) ^ ((srw & 7) << 4)));
        a = __builtin_amdgcn_mfma_f32_16x16x32_bf16(qa[kb], kf, a, 0, 0, 0);
      }
      S[cb] = a;
      const bf16x8 jw = *(const bf16x8*)(Jwpk + ((jb + s0 + cb * 16 + lr) << 4) + g * 4);
      Sb[cb] = __builtin_amdgcn_mfma_f32_16x16x32_bf16(ra, jw, zf, 0, 0, 0);
    }
    __builtin_amdgcn_s_setprio(0);

    const bool diag = (s0 == t0);
    float logit[4][4];
#pragma unroll
    for (int cb = 0; cb < 4; ++cb) {
#pragma unroll
      for (int r = 0; r < 4; ++r) {
        float lg = S[cb][r] * 0.125f + fabsf(Sb[cb][r]) * bsc;
        if (diag && (cb * 16 + lr > w * 16 + 4 * g + r)) lg = -1e30f;
        logit[cb][r] = lg;
      }
    }
    float mxr[4];
#pragma unroll
    for (int r = 0; r < 4; ++r) {
      float mx = fmaxf(fmaxf(logit[0][r], logit[1][r]), fmaxf(logit[2][r], logit[3][r]));
      mx = fmaxf(mx, __shfl_xor(mx, 1));
      mx = fmaxf(mx, __shfl_xor(mx, 2));
      mx = fmaxf(mx, __shfl_xor(mx, 4));
      mx = fmaxf(mx, __shfl_xor(mx, 8));
      mxr[r] = mx;
    }
    // defer-max (T13): rescale only when a row's max grew past threshold
    bool need = false;
#pragma unroll
    for (int r = 0; r < 4; ++r) need = need || (mxr[r] > m[r] + 8.f);
    if (__any(need)) {
#pragma unroll
      for (int r = 0; r < 4; ++r) {
        const float nm = fmaxf(m[r], mxr[r]);
        const float sc = __expf(m[r] - nm);
        m[r] = nm;
        lsum[r] *= sc;
#pragma unroll
        for (int d = 0; d < 4; ++d) O[d][r] *= sc;
      }
    }
#pragma unroll
    for (int cb = 0; cb < 4; ++cb) {
#pragma unroll
      for (int r = 0; r < 4; ++r) {
        const float p = __expf(logit[cb][r] - m[r]);
        lsum[r] += p;
        const int q = 4 * g + r;
        const int s = cb * 16 + lr;
        const int byte = w * 2048 + q * 128 + ((2 * s) ^ ((q & 7) << 4));
        *(unsigned short*)(PB + byte) = f2bf(p);
      }
    }
    asm volatile("s_waitcnt lgkmcnt(0)" ::: "memory");
    __builtin_amdgcn_sched_barrier(0);

    bf16x8 pa[2];
#pragma unroll
    for (int kb = 0; kb < 2; ++kb) {
      const int byte = w * 2048 + lr * 128 + (((kb * 64) + 16 * g) ^ ((lr & 7) << 4));
      pa[kb] = *(const bf16x8*)(PB + byte);
    }
    const unsigned char* vtb = VT + buf * 8192;
    __builtin_amdgcn_s_setprio(1);
#pragma unroll
    for (int db = 0; db < 4; ++db) {
      const int d = db * 16 + lr;
#pragma unroll
      for (int kb = 0; kb < 2; ++kb) {
        const int byte = d * 128 + (((kb * 64) + 16 * g) ^ ((d & 7) << 4));
        const bf16x8 vf = *(const bf16x8*)(vtb + byte);
        O[db] = __builtin_amdgcn_mfma_f32_16x16x32_bf16(pa[kb], vf, O[db], 0, 0, 0);
      }
    }
    __builtin_amdgcn_s_setprio(0);
#pragma unroll
    for (int i = 0; i < 4; ++i) kA[i] = kN[i];
    vA0 = vN0; vA1 = vN1; vA2 = vN2; vA3 = vN3;
  }

#pragma unroll
  for (int r = 0; r < 4; ++r) {
    float l = lsum[r];
    l += __shfl_xor(l, 1);
    l += __shfl_xor(l, 2);
    l += __shfl_xor(l, 4);
    l += __shfl_xor(l, 8);
    lsum[r] = 1.f / l;
  }
  {
    const int qb = w * 16 + 4 * g;
#pragma unroll
    for (int db = 0; db < 4; ++db) {
#pragma unroll
      for (int r = 0; r < 4; ++r) {
        const int t = t0 + qb + r;
        attnout[(size_t)(b * T_ + t) * 1024 + h * 64 + db * 16 + lr] = O[db][r] * lsum[r];
      }
    }
  }
}

// =============================== launcher ===============================
extern "C" void kernel_launch(void* const* d_in, const int* in_sizes, int n_in,
                              void* d_out, int out_size, void* d_ws, size_t ws_size,
                              hipStream_t stream)
{
  (void)in_sizes; (void)n_in; (void)out_size; (void)ws_size;
  const float* x    = (const float*)d_in[0];
  const float* Wqkv = (const float*)d_in[1];
  const float* bqkv = (const float*)d_in[2];
  const float* W1w  = (const float*)d_in[3];
  const float* W2w  = (const float*)d_in[4];
  const float* W1r  = (const float*)d_in[5];
  const float* W2r  = (const float*)d_in[6];
  const float* bsc  = (const float*)d_in[7];
  const float* Wout = (const float*)d_in[8];
  const float* bout = (const float*)d_in[9];
  float* out = (float*)d_out;

  float*    qkvp    = (float*)d_ws;                     // 2048*3328 f
  unsigned* Jwpk    = (unsigned*)(qkvp + (size_t)2048 * NA_);  // 524288 u32
  unsigned* rdMpk   = Jwpk + 524288;                    // 524288 u32
  float*    attnout = (float*)(rdMpk + 524288);         // 2097152 f

  gemm_qkv<<<dim3(26, 16), 512, 0, stream>>>(
      x, Wqkv, bqkv, W1w, W2w, W1r, W2r, qkvp);
  scan_kernel<<<dim3(B_ * H_), 256, 0, stream>>>(qkvp, Jwpk, rdMpk);
  attn_mfma<<<dim3(B_ * H_ * (T_ / 64)), 256, 0, stream>>>(
      qkvp, Jwpk, rdMpk, bsc, attnout);
  gemm_out<<<dim3(8, 16), 512, 0, stream>>>(attnout, Wout, bout, out);
}